// Round 4
// baseline (745.038 us; speedup 1.0000x reference)
//
#include <hip/hip_runtime.h>
#include <hip/hip_bf16.h>

#define TT 4096
#define SS 4096
#define DD 128
#define HUGEV 1e30f

#define RR 8                    // rows per lane
#define KK 8                    // cols per super-step
#define BH (64 * RR)            // band height = 512
#define NBANDS (TT / BH)        // 8
#define NCHUNK (SS / KK)        // 512 col-chunks per band
#define NSIG 576                // sigma slots (tc + lane: 0..574, padded)
#define NG 72                   // 72 groups x 8 steps = 576 super-steps

// DPP wave_shr:1 — lane l receives lane l-1's src; lane 0 receives `old`.
__device__ __forceinline__ float shr1(float oldv, float src) {
  return __uint_as_float((unsigned)__builtin_amdgcn_update_dpp(
      (int)__float_as_uint(oldv), (int)__float_as_uint(src),
      0x138 /*wave_shr:1*/, 0xf, 0xf, false));
}

// ---------------- init: zero progress flags, write-through (graph replay!) ----
__global__ __launch_bounds__(64) void dtw_init(int* __restrict__ progress) {
  __hip_atomic_store(progress + threadIdx.x, 0, __ATOMIC_RELAXED,
                     __HIP_MEMORY_SCOPE_AGENT);
}

// ---------------- row norms ----------------
__global__ __launch_bounds__(256) void dtw_norms(const float* __restrict__ ref,
                                                 const float* __restrict__ tgt,
                                                 float* __restrict__ r2,
                                                 float* __restrict__ t2) {
  int i = blockIdx.x * 256 + threadIdx.x;
  const float* p = (i < TT) ? (ref + (size_t)i * DD) : (tgt + (size_t)(i - TT) * DD);
  float s = 0.f;
#pragma unroll
  for (int k = 0; k < DD; k += 4) {
    float4 v = *(const float4*)(p + k);
    s = fmaf(v.x, v.x, s); s = fmaf(v.y, v.y, s);
    s = fmaf(v.z, v.z, s); s = fmaf(v.w, v.w, s);
  }
  if (i < TT) r2[i] = s; else t2[i - TT] = s;
}

// ---------------- dist -> skewed tile layout, bf16 ----------------
// Element (i,j): b=i>>9, lane=(i>>3)&63, r=i&7, tc=j>>3, k=j&7, sigma=tc+lane.
// ushort index = ((b*NSIG + sigma)*64 + lane)*64 + r*8 + k.
__global__ __launch_bounds__(256) void dtw_dist(const float* __restrict__ ref,
                                                const float* __restrict__ tgt,
                                                const float* __restrict__ r2,
                                                const float* __restrict__ t2,
                                                unsigned short* __restrict__ dist) {
  __shared__ float As[32][68];
  __shared__ float Bs[32][68];
  const int tid = threadIdx.x;
  const int tx = tid & 15, ty = tid >> 4;
  const int i0 = blockIdx.y * 64, j0 = blockIdx.x * 64;
  const int lrow = tid >> 3;
  const int lk = (tid & 7) << 2;
  const float* ap = ref + (size_t)(i0 + lrow) * DD + lk;
  const float* bp = tgt + (size_t)(j0 + lrow) * DD + lk;
  float acc[4][4] = {};
  for (int k0 = 0; k0 < DD; k0 += 32) {
    float4 a0 = *(const float4*)(ap + k0);
    float4 a1 = *(const float4*)(ap + k0 + 32 * DD);
    float4 b0 = *(const float4*)(bp + k0);
    float4 b1 = *(const float4*)(bp + k0 + 32 * DD);
    __syncthreads();
    As[lk + 0][lrow] = a0.x; As[lk + 1][lrow] = a0.y; As[lk + 2][lrow] = a0.z; As[lk + 3][lrow] = a0.w;
    As[lk + 0][lrow + 32] = a1.x; As[lk + 1][lrow + 32] = a1.y; As[lk + 2][lrow + 32] = a1.z; As[lk + 3][lrow + 32] = a1.w;
    Bs[lk + 0][lrow] = b0.x; Bs[lk + 1][lrow] = b0.y; Bs[lk + 2][lrow] = b0.z; Bs[lk + 3][lrow] = b0.w;
    Bs[lk + 0][lrow + 32] = b1.x; Bs[lk + 1][lrow + 32] = b1.y; Bs[lk + 2][lrow + 32] = b1.z; Bs[lk + 3][lrow + 32] = b1.w;
    __syncthreads();
#pragma unroll
    for (int k = 0; k < 32; ++k) {
      float4 av = *(const float4*)&As[k][ty << 2];
      float4 bv = *(const float4*)&Bs[k][tx << 2];
      float aa[4] = {av.x, av.y, av.z, av.w};
      float bb[4] = {bv.x, bv.y, bv.z, bv.w};
#pragma unroll
      for (int r = 0; r < 4; ++r)
#pragma unroll
        for (int c = 0; c < 4; ++c) acc[r][c] = fmaf(aa[r], bb[c], acc[r][c]);
    }
  }
#pragma unroll
  for (int r = 0; r < 4; ++r) {
    const int i = i0 + (ty << 2) + r;
    const float ri = r2[i];
    unsigned short oo[4];
#pragma unroll
    for (int c = 0; c < 4; ++c) {
      int j = j0 + (tx << 2) + c;
      float d2 = ri + t2[j] - 2.0f * acc[r][c];
      float dd = sqrtf(fmaxf(d2, 0.f));
      unsigned bits = __float_as_uint(dd);
      oo[c] = (unsigned short)((bits + 0x7FFFu + ((bits >> 16) & 1u)) >> 16);
    }
    ushort4 ov; ov.x = oo[0]; ov.y = oo[1]; ov.z = oo[2]; ov.w = oo[3];
    const int jj = j0 + (tx << 2);
    const int bnd = i >> 9, ln = (i >> 3) & 63, rr = i & 7;
    const int tc = jj >> 3, kk0 = jj & 7;
    const size_t idx =
        ((((size_t)bnd * NSIG + tc + ln) << 6) + (size_t)ln) * 64 + rr * 8 + kk0;
    *reinterpret_cast<ushort4*>(dist + idx) = ov;
  }
}

// ---------------- banded wavefront DP ----------------
// Band b = rows [512b, 512b+512); lane l owns rows 512b+8l..+8l+7.
// Super-step sigma: lane l computes tile-col c = sigma - l.
// Cross-lane handoff: DPP wave_shr:1 (lane0 injected from upb LDS broadcast).
// Cross-band: brow written as relaxed agent u64 atomics (write-through),
// flag ordered by bare s_waitcnt vmcnt(0) + relaxed store. Polls are relaxed
// read-through loads -> NO cache invalidation anywhere in the loop.

#define STEP(G, S, BUF)                                                        \
  {                                                                            \
    const int sigma = 8 * (G) + (S);                                           \
    float4 ub0 = *(const float4*)&upb[8 * (((S) + 1) & 7)];                    \
    float4 ub1 = *(const float4*)&upb[8 * (((S) + 1) & 7) + 4];                \
    float uba[8] = {ub0.x, ub0.y, ub0.z, ub0.w, ub1.x, ub1.y, ub1.z, ub1.w};   \
    float bot[KK];                                                             \
    float ul = ul_top;                                                         \
    _Pragma("unroll")                                                          \
    for (int k = 0; k < KK; ++k) {                                             \
      const float uin = u[k];                                                  \
      float up = uin;                                                          \
      float ulr = ul;                                                          \
      _Pragma("unroll")                                                        \
      for (int r = 0; r < RR; ++r) {                                           \
        unsigned w = ((k >> 1) == 0) ? BUF[r].x                                \
                   : ((k >> 1) == 1) ? BUF[r].y                                \
                   : ((k >> 1) == 2) ? BUF[r].z : BUF[r].w;                    \
        float dv = (k & 1) ? __uint_as_float(w & 0xffff0000u)                  \
                           : __uint_as_float(w << 16);                         \
        float diag = left[r];                                                  \
        float nv = dv + fminf(fminf(up, ulr), left[r]);                        \
        left[r] = nv;                                                          \
        ulr = diag;                                                            \
        up = nv;                                                               \
      }                                                                        \
      bot[k] = up;                                                             \
      u[k] = shr1(uba[k], up);                                                 \
      ul = uin;                                                                \
    }                                                                          \
    ul_top = ul;                                                               \
    const int c = sigma - lane;                                                \
    const bool cvalid = (c >= 0) && (c < NCHUNK);                              \
    if (lane == 63 && cvalid && b < NBANDS - 1) {                              \
      unsigned long long* bq =                                                 \
          (unsigned long long*)(brow + (size_t)b * SS + (size_t)c * KK);       \
      _Pragma("unroll")                                                        \
      for (int h = 0; h < 4; ++h) {                                            \
        unsigned long long pv =                                                \
            ((unsigned long long)__float_as_uint(bot[2 * h + 1]) << 32) |      \
            (unsigned long long)__float_as_uint(bot[2 * h]);                   \
        __hip_atomic_store(bq + h, pv, __ATOMIC_RELAXED,                       \
                           __HIP_MEMORY_SCOPE_AGENT);                          \
      }                                                                        \
    }                                                                          \
    if (cvalid && c == NCHUNK - 1) ans = bot[KK - 1];                          \
    if ((S) == 6 && b < NBANDS - 1 && (G) >= 8) {                              \
      asm volatile("s_waitcnt vmcnt(0)" ::: "memory");                         \
      if (lane == 63)                                                          \
        __hip_atomic_store(progress + b, (G)-7, __ATOMIC_RELAXED,              \
                           __HIP_MEMORY_SCOPE_AGENT);                          \
    }                                                                          \
    {                                                                          \
      int sp = sigma + 4; sp = sp > (NSIG - 1) ? (NSIG - 1) : sp;              \
      const unsigned short* tp = tb + (((size_t)sp << 6) + lane) * 64;         \
      _Pragma("unroll")                                                        \
      for (int q = 0; q < RR; ++q) BUF[q] = *(const uint4*)(tp + q * 8);       \
    }                                                                          \
  }

__global__ __launch_bounds__(64) void dtw_dp(const unsigned short* __restrict__ dist,
                                             float* __restrict__ brow,
                                             int* __restrict__ progress,
                                             float* __restrict__ out) {
  const int b = blockIdx.x;
  const int lane = threadIdx.x;
  __shared__ __align__(16) float upb[64];
  const unsigned short* tb = dist + (size_t)b * NSIG * 64 * 64;

  upb[lane] = HUGEV;   // band 0 (and pre-load default) boundary = +inf

  float left[RR];
#pragma unroll
  for (int r = 0; r < RR; ++r) left[r] = HUGEV;
  float u[KK];
#pragma unroll
  for (int k = 0; k < KK; ++k) u[k] = HUGEV;
  float ul_top = (b == 0 && lane == 0) ? 0.f : HUGEV;
  float ans = 0.f;

  uint4 dqA[RR], dqB[RR], dqC[RR], dqD[RR];
#pragma unroll
  for (int q = 0; q < RR; ++q) {
    dqA[q] = *(const uint4*)(tb + (((size_t)0 << 6) + lane) * 64 + q * 8);
    dqB[q] = *(const uint4*)(tb + (((size_t)1 << 6) + lane) * 64 + q * 8);
    dqC[q] = *(const uint4*)(tb + (((size_t)2 << 6) + lane) * 64 + q * 8);
    dqD[q] = *(const uint4*)(tb + (((size_t)3 << 6) + lane) * 64 + q * 8);
  }

  for (int g = 0; g < NG; ++g) {
    if (b > 0 && g < (NCHUNK / 8)) {
      const int want = g + 1;
      while (__hip_atomic_load(progress + (b - 1), __ATOMIC_RELAXED,
                               __HIP_MEMORY_SCOPE_AGENT) < want)
        __builtin_amdgcn_s_sleep(8);
      // fresh read-through of the boundary row (no L2 allocation/invalidation)
      upb[lane] = __hip_atomic_load(brow + (size_t)(b - 1) * SS + 64 * g + lane,
                                    __ATOMIC_RELAXED, __HIP_MEMORY_SCOPE_AGENT);
    }
    {  // lane-0 u fix-up from upb[0..8) (branchless cndmask)
      float4 h0 = *(const float4*)&upb[0];
      float4 h1 = *(const float4*)&upb[4];
      float hh[8] = {h0.x, h0.y, h0.z, h0.w, h1.x, h1.y, h1.z, h1.w};
#pragma unroll
      for (int k = 0; k < KK; ++k) u[k] = (lane == 0) ? hh[k] : u[k];
    }
    STEP(g, 0, dqA)
    STEP(g, 1, dqB)
    STEP(g, 2, dqC)
    STEP(g, 3, dqD)
    STEP(g, 4, dqA)
    STEP(g, 5, dqB)
    STEP(g, 6, dqC)
    STEP(g, 7, dqD)
  }
  if (b == NBANDS - 1 && lane == 63) out[0] = ans;
}

extern "C" void kernel_launch(void* const* d_in, const int* in_sizes, int n_in,
                              void* d_out, int out_size, void* d_ws, size_t ws_size,
                              hipStream_t stream) {
  const float* ref = (const float*)d_in[0];
  const float* tgt = (const float*)d_in[1];
  float* out = (float*)d_out;
  char* ws = (char*)d_ws;
  unsigned short* dist = (unsigned short*)ws;       // skewed tiles: 37,748,736 B
  size_t off = (size_t)NBANDS * NSIG * 64 * 64 * 2;
  float* brow = (float*)(ws + off);      off += (size_t)64 * SS * 4;
  int* progress = (int*)(ws + off);      off += 1024;
  float* r2 = (float*)(ws + off);        off += (size_t)TT * 4;
  float* t2 = (float*)(ws + off);

  dtw_init<<<1, 64, 0, stream>>>(progress);
  dtw_norms<<<(TT + SS) / 256, 256, 0, stream>>>(ref, tgt, r2, t2);
  dtw_dist<<<dim3(SS / 64, TT / 64), 256, 0, stream>>>(ref, tgt, r2, t2, dist);
  dtw_dp<<<NBANDS, 64, 0, stream>>>(dist, brow, progress, out);
}